// Round 2
// baseline (427.835 us; speedup 1.0000x reference)
//
#include <hip/hip_runtime.h>
#include <math.h>

#define IN_CH 128
#define HCDIM 64
#define NHEAD 4
#define NEG_SLOPE 0.2f

static inline size_t align256(size_t x){ return (x + 255) & ~(size_t)255; }

// ---------------------------------------------------------------------------
// Fused GEMM (x @ W) + per-node attention halves a_src/a_dst.
// Tile: 32 rows x 64 cols per block (256 threads). W (128x64, 32KB) fully in
// LDS; x tile staged [32][132] (pad 4 floats -> conflict-free broadcast reads).
// Each thread: 2 rows x 4 cols micro-tile.
// ---------------------------------------------------------------------------
__global__ __launch_bounds__(256) void gemm_att_kernel(
    const float* __restrict__ x, const float* __restrict__ W,
    const float* __restrict__ attS, const float* __restrict__ attD,
    float* __restrict__ xp, float* __restrict__ a_src, float* __restrict__ a_dst,
    int N)
{
    __shared__ __align__(16) float wlds[IN_CH * HCDIM];   // 32 KB
    __shared__ __align__(16) float xlds[32 * 132];        // 16.9 KB
    const int t = threadIdx.x;
    const int rows0 = blockIdx.x * 32;

    // stage W (linear, coalesced float4)
    #pragma unroll
    for (int j = 0; j < 8; ++j) {
        int i = j * 256 + t;                   // 2048 float4s
        ((float4*)wlds)[i] = ((const float4*)W)[i];
    }
    // stage x tile: 32 rows x 128 = 1024 float4s
    #pragma unroll
    for (int j = 0; j < 4; ++j) {
        int i  = j * 256 + t;
        int r  = i >> 5;
        int kq = i & 31;
        int row = rows0 + r;
        float4 v = make_float4(0.f, 0.f, 0.f, 0.f);
        if (row < N) v = *(const float4*)&x[(size_t)row * IN_CH + kq * 4];
        *(float4*)&xlds[r * 132 + kq * 4] = v;
    }
    __syncthreads();

    const int rg = t >> 4;      // 0..15  -> row pair
    const int cg = t & 15;      // 0..15  -> col quad
    float acc0[4] = {0.f, 0.f, 0.f, 0.f};
    float acc1[4] = {0.f, 0.f, 0.f, 0.f};
    const float* xb0 = &xlds[(rg * 2 + 0) * 132];
    const float* xb1 = &xlds[(rg * 2 + 1) * 132];

    #pragma unroll 4
    for (int k = 0; k < IN_CH; ++k) {
        float4 b = *(const float4*)&wlds[k * HCDIM + cg * 4];
        float a0 = xb0[k];
        float a1 = xb1[k];
        acc0[0] = fmaf(a0, b.x, acc0[0]);
        acc0[1] = fmaf(a0, b.y, acc0[1]);
        acc0[2] = fmaf(a0, b.z, acc0[2]);
        acc0[3] = fmaf(a0, b.w, acc0[3]);
        acc1[0] = fmaf(a1, b.x, acc1[0]);
        acc1[1] = fmaf(a1, b.y, acc1[1]);
        acc1[2] = fmaf(a1, b.z, acc1[2]);
        acc1[3] = fmaf(a1, b.w, acc1[3]);
    }

    float sv[4], dv[4];
    #pragma unroll
    for (int j = 0; j < 4; ++j) { sv[j] = attS[cg * 4 + j]; dv[j] = attD[cg * 4 + j]; }

    #pragma unroll
    for (int i = 0; i < 2; ++i) {
        const float* accp = i ? acc1 : acc0;
        int row = rows0 + rg * 2 + i;
        bool ok = row < N;
        if (ok) {
            *(float4*)&xp[(size_t)row * HCDIM + cg * 4] =
                make_float4(accp[0], accp[1], accp[2], accp[3]);
        }
        float ps = accp[0]*sv[0] + accp[1]*sv[1] + accp[2]*sv[2] + accp[3]*sv[3];
        float pd = accp[0]*dv[0] + accp[1]*dv[1] + accp[2]*dv[2] + accp[3]*dv[3];
        // reduce over the 4 threads (cg quad) that cover one head's 16 cols
        ps += __shfl_xor(ps, 1); ps += __shfl_xor(ps, 2);
        pd += __shfl_xor(pd, 1); pd += __shfl_xor(pd, 2);
        if (ok && (cg & 3) == 0) {
            int h = cg >> 2;
            a_src[(size_t)row * NHEAD + h] = ps;
            a_dst[(size_t)row * NHEAD + h] = pd;
        }
    }
}

// ---------------------------------------------------------------------------
// CSR construction: histogram -> 2-level exclusive scan -> scatter
// ---------------------------------------------------------------------------
__global__ void hist_kernel(const int* __restrict__ dstv, int E, int* __restrict__ counts)
{
    int i = blockIdx.x * blockDim.x + threadIdx.x;
    if (i < E) atomicAdd(&counts[dstv[i]], 1);
}

__global__ __launch_bounds__(256) void scan_bsum(
    const int* __restrict__ counts, int N, int* __restrict__ bsums)
{
    __shared__ int sdata[256];
    const int b = blockIdx.x, t = threadIdx.x;
    int base = b * 2048 + t * 8;
    int s = 0;
    #pragma unroll
    for (int i = 0; i < 8; ++i) {
        int g = base + i;
        if (g < N) s += counts[g];
    }
    sdata[t] = s;
    __syncthreads();
    for (int off = 128; off > 0; off >>= 1) {
        if (t < off) sdata[t] += sdata[t + off];
        __syncthreads();
    }
    if (t == 0) bsums[b] = sdata[0];
}

__global__ void scan_offsets(const int* __restrict__ bsums, int nblk,
                             int* __restrict__ boffs, int* __restrict__ row_start,
                             int N, int E)
{
    if (threadIdx.x == 0 && blockIdx.x == 0) {
        int run = 0;
        for (int b = 0; b < nblk; ++b) { boffs[b] = run; run += bsums[b]; }
        row_start[N] = E;
    }
}

__global__ __launch_bounds__(256) void scan_write(
    const int* __restrict__ counts, int N, const int* __restrict__ boffs,
    int* __restrict__ row_start, int* __restrict__ cursor)
{
    __shared__ int tsum[256];
    __shared__ int tex[256];
    const int b = blockIdx.x, t = threadIdx.x;
    int base = b * 2048 + t * 8;
    int v[8];
    int s = 0;
    #pragma unroll
    for (int i = 0; i < 8; ++i) {
        int g = base + i;
        v[i] = (g < N) ? counts[g] : 0;
        s += v[i];
    }
    tsum[t] = s;
    __syncthreads();
    if (t == 0) {
        int run = 0;
        for (int i = 0; i < 256; ++i) { tex[i] = run; run += tsum[i]; }
    }
    __syncthreads();
    int run = boffs[b] + tex[t];
    #pragma unroll
    for (int i = 0; i < 8; ++i) {
        int g = base + i;
        if (g < N) {
            row_start[g] = run;
            cursor[g]    = run;
            run += v[i];
        }
    }
}

__global__ void scatter_kernel(const int* __restrict__ srcv, const int* __restrict__ dstv,
                               int E, int* __restrict__ cursor,
                               int* __restrict__ eid_list, int* __restrict__ src_list)
{
    int i = blockIdx.x * blockDim.x + threadIdx.x;
    if (i < E) {
        int d = dstv[i];
        int pos = atomicAdd(&cursor[d], 1);
        eid_list[pos] = i;
        src_list[pos] = srcv[i];
    }
}

// ---------------------------------------------------------------------------
// edge_index passthrough as VALUES (harness reads d_out as float32):
// out1[i] = (float)ei[i]. Indices < 2^24 so exact.
// ---------------------------------------------------------------------------
__global__ void ei_to_float_kernel(const int* __restrict__ ei,
                                   float* __restrict__ out1, int n)
{
    int i = blockIdx.x * blockDim.x + threadIdx.x;
    if (i < n) out1[i] = (float)ei[i];
}

// ---------------------------------------------------------------------------
// One wave per destination node: chunked (<=64 edges/chunk) softmax
// (max -> sum -> alpha) with lane=edge, then aggregation with lane=channel
// (coalesced 256B gathers of xp[src]). No atomics, deterministic per node.
// ---------------------------------------------------------------------------
__global__ __launch_bounds__(256) void aggregate_kernel(
    const float* __restrict__ xp, const float* __restrict__ a_src,
    const float* __restrict__ a_dst, const float* __restrict__ bias,
    const int* __restrict__ row_start, const int* __restrict__ eid_list,
    const int* __restrict__ src_list,
    float* __restrict__ out, float* __restrict__ alpha_out, int N)
{
    __shared__ __align__(16) float al_f[4][256];  // per-wave: 64 edges x 4 heads
    __shared__ int sr[4][64];
    const int w    = threadIdx.x >> 6;
    const int lane = threadIdx.x & 63;
    const int n    = blockIdx.x * 4 + w;
    if (n >= N) return;

    const int beg = row_start[n];
    const int end = row_start[n + 1];
    const float bv = bias[lane];
    if (beg >= end) {                       // empty segment: out = bias
        out[(size_t)n * HCDIM + lane] = bv;
        return;
    }

    const float4 ad = *(const float4*)&a_dst[(size_t)n * NHEAD];

    // ---- phase 1: segment max per head ----
    float m0 = -INFINITY, m1 = -INFINITY, m2 = -INFINITY, m3 = -INFINITY;
    for (int cb = beg; cb < end; cb += 64) {
        int idx = cb + lane;
        if (idx < end) {
            int s = src_list[idx];
            float4 as = *(const float4*)&a_src[(size_t)s * NHEAD];
            float z0 = as.x + ad.x; z0 = z0 > 0.f ? z0 : NEG_SLOPE * z0;
            float z1 = as.y + ad.y; z1 = z1 > 0.f ? z1 : NEG_SLOPE * z1;
            float z2 = as.z + ad.z; z2 = z2 > 0.f ? z2 : NEG_SLOPE * z2;
            float z3 = as.w + ad.w; z3 = z3 > 0.f ? z3 : NEG_SLOPE * z3;
            m0 = fmaxf(m0, z0); m1 = fmaxf(m1, z1);
            m2 = fmaxf(m2, z2); m3 = fmaxf(m3, z3);
        }
    }
    #pragma unroll
    for (int off = 1; off < 64; off <<= 1) {
        m0 = fmaxf(m0, __shfl_xor(m0, off));
        m1 = fmaxf(m1, __shfl_xor(m1, off));
        m2 = fmaxf(m2, __shfl_xor(m2, off));
        m3 = fmaxf(m3, __shfl_xor(m3, off));
    }

    // ---- phase 2: denominator ----
    float t0 = 0.f, t1 = 0.f, t2 = 0.f, t3 = 0.f;
    for (int cb = beg; cb < end; cb += 64) {
        int idx = cb + lane;
        if (idx < end) {
            int s = src_list[idx];
            float4 as = *(const float4*)&a_src[(size_t)s * NHEAD];
            float z0 = as.x + ad.x; z0 = z0 > 0.f ? z0 : NEG_SLOPE * z0;
            float z1 = as.y + ad.y; z1 = z1 > 0.f ? z1 : NEG_SLOPE * z1;
            float z2 = as.z + ad.z; z2 = z2 > 0.f ? z2 : NEG_SLOPE * z2;
            float z3 = as.w + ad.w; z3 = z3 > 0.f ? z3 : NEG_SLOPE * z3;
            t0 += __expf(z0 - m0); t1 += __expf(z1 - m1);
            t2 += __expf(z2 - m2); t3 += __expf(z3 - m3);
        }
    }
    #pragma unroll
    for (int off = 1; off < 64; off <<= 1) {
        t0 += __shfl_xor(t0, off);
        t1 += __shfl_xor(t1, off);
        t2 += __shfl_xor(t2, off);
        t3 += __shfl_xor(t3, off);
    }
    const float r0 = 1.f / (t0 + 1e-16f);
    const float r1 = 1.f / (t1 + 1e-16f);
    const float r2 = 1.f / (t2 + 1e-16f);
    const float r3 = 1.f / (t3 + 1e-16f);

    // ---- phase 3: alpha + aggregation ----
    const int h = lane >> 4;        // my output channel's head
    float acc = 0.f;
    for (int cb = beg; cb < end; cb += 64) {
        int idx = cb + lane;
        int nE = min(64, end - cb);
        if (idx < end) {
            int s = src_list[idx];
            float4 as = *(const float4*)&a_src[(size_t)s * NHEAD];
            float z0 = as.x + ad.x; z0 = z0 > 0.f ? z0 : NEG_SLOPE * z0;
            float z1 = as.y + ad.y; z1 = z1 > 0.f ? z1 : NEG_SLOPE * z1;
            float z2 = as.z + ad.z; z2 = z2 > 0.f ? z2 : NEG_SLOPE * z2;
            float z3 = as.w + ad.w; z3 = z3 > 0.f ? z3 : NEG_SLOPE * z3;
            float e0 = __expf(z0 - m0) * r0;
            float e1 = __expf(z1 - m1) * r1;
            float e2 = __expf(z2 - m2) * r2;
            float e3 = __expf(z3 - m3) * r3;
            int eid = eid_list[idx];
            *(float4*)&alpha_out[(size_t)eid * NHEAD] = make_float4(e0, e1, e2, e3);
            *(float4*)&al_f[w][lane * 4] = make_float4(e0, e1, e2, e3);
            sr[w][lane] = s;
        }
        for (int j = 0; j < nE; ++j) {
            float a  = al_f[w][j * 4 + h];          // broadcast (4 addrs)
            int   sj = sr[w][j];                    // broadcast
            acc = fmaf(a, xp[(size_t)sj * HCDIM + lane], acc);  // coalesced 256B
        }
    }
    out[(size_t)n * HCDIM + lane] = acc + bv;
}

// ---------------------------------------------------------------------------
extern "C" void kernel_launch(void* const* d_in, const int* in_sizes, int n_in,
                              void* d_out, int out_size, void* d_ws, size_t ws_size,
                              hipStream_t stream)
{
    const float* x    = (const float*)d_in[0];
    const float* W    = (const float*)d_in[1];
    const float* attS = (const float*)d_in[2];
    const float* attD = (const float*)d_in[3];
    const float* bias = (const float*)d_in[4];
    const int*   ei   = (const int*)d_in[5];

    const int N = in_sizes[0] / IN_CH;
    const int E = in_sizes[5] / 2;
    const int* srcv = ei;
    const int* dstv = ei + E;

    // workspace carve-up (all 256B aligned)
    char* p = (char*)d_ws;
    float* xp        = (float*)p; p += align256((size_t)N * HCDIM * 4);
    float* a_src     = (float*)p; p += align256((size_t)N * NHEAD * 4);
    float* a_dst     = (float*)p; p += align256((size_t)N * NHEAD * 4);
    int*   counts    = (int*)p;   p += align256((size_t)N * 4);
    int*   cursor    = (int*)p;   p += align256((size_t)N * 4);
    int*   row_start = (int*)p;   p += align256(((size_t)N + 1) * 4);
    int*   bsums     = (int*)p;   p += align256(1024 * 4);
    int*   boffs    = (int*)p;    p += align256(1024 * 4);
    int*   eid_list  = (int*)p;   p += align256((size_t)E * 4);
    int*   src_list  = (int*)p;   p += align256((size_t)E * 4);

    float* out       = (float*)d_out;
    float* out_ei    = out + (size_t)N * HCDIM;
    float* alpha_out = out_ei + 2 * (size_t)E;

    hipMemsetAsync(counts, 0, (size_t)N * 4, stream);

    gemm_att_kernel<<<(N + 31) / 32, 256, 0, stream>>>(
        x, W, attS, attD, xp, a_src, a_dst, N);

    hist_kernel<<<(E + 255) / 256, 256, 0, stream>>>(dstv, E, counts);

    const int nblk = (N + 2047) / 2048;
    scan_bsum<<<nblk, 256, 0, stream>>>(counts, N, bsums);
    scan_offsets<<<1, 64, 0, stream>>>(bsums, nblk, boffs, row_start, N, E);
    scan_write<<<nblk, 256, 0, stream>>>(counts, N, boffs, row_start, cursor);

    scatter_kernel<<<(E + 255) / 256, 256, 0, stream>>>(
        srcv, dstv, E, cursor, eid_list, src_list);

    aggregate_kernel<<<(N + 3) / 4, 256, 0, stream>>>(
        xp, a_src, a_dst, bias, row_start, eid_list, src_list, out, alpha_out, N);

    // edge_index passthrough as float values (output #2)
    ei_to_float_kernel<<<(2 * E + 255) / 256, 256, 0, stream>>>(ei, out_ei, 2 * E);
}

// Round 4
// 414.252 us; speedup vs baseline: 1.0328x; 1.0328x over previous
//
#include <hip/hip_runtime.h>
#include <hip/hip_bf16.h>
#include <math.h>

#define IN_CH 128
#define HCDIM 64
#define NHEAD 4
#define NEG_SLOPE 0.2f

static inline size_t align256(size_t x){ return (x + 255) & ~(size_t)255; }

__device__ __forceinline__ float bf2f(__hip_bfloat16 h) { return __bfloat162float(h); }

// ---------------------------------------------------------------------------
// Fused front kernel:
//   blocks [0, GB)          : GEMM (x @ W) + attention halves, xp stored bf16
//   blocks [GB, GB+CB)      : ei -> float passthrough + dst histogram
// ---------------------------------------------------------------------------
__global__ __launch_bounds__(256) void front_kernel(
    const float* __restrict__ x, const float* __restrict__ W,
    const float* __restrict__ attS, const float* __restrict__ attD,
    __hip_bfloat16* __restrict__ xpb, float* __restrict__ a_src, float* __restrict__ a_dst,
    int N, int GB,
    const int* __restrict__ ei, int E,
    float* __restrict__ out_ei, int* __restrict__ counts)
{
    __shared__ __align__(16) float wlds[IN_CH * HCDIM];   // 32 KB
    __shared__ __align__(16) float xlds[32 * 132];        // 16.9 KB
    const int t = threadIdx.x;

    if ((int)blockIdx.x >= GB) {
        // ---- histogram + edge_index float conversion ----
        int idx = ((int)blockIdx.x - GB) * 256 + t;
        if (idx < 2 * E) out_ei[idx] = (float)ei[idx];
        if (idx < E)     atomicAdd(&counts[ei[E + idx]], 1);
        return;
    }

    const int rows0 = blockIdx.x * 32;

    // stage W (linear, coalesced float4)
    #pragma unroll
    for (int j = 0; j < 8; ++j) {
        int i = j * 256 + t;                   // 2048 float4s
        ((float4*)wlds)[i] = ((const float4*)W)[i];
    }
    // stage x tile: 32 rows x 128 = 1024 float4s
    #pragma unroll
    for (int j = 0; j < 4; ++j) {
        int i  = j * 256 + t;
        int r  = i >> 5;
        int kq = i & 31;
        int row = rows0 + r;
        float4 v = make_float4(0.f, 0.f, 0.f, 0.f);
        if (row < N) v = *(const float4*)&x[(size_t)row * IN_CH + kq * 4];
        *(float4*)&xlds[r * 132 + kq * 4] = v;
    }
    __syncthreads();

    const int rg = t >> 4;      // 0..15  -> row pair
    const int cg = t & 15;      // 0..15  -> col quad
    float acc0[4] = {0.f, 0.f, 0.f, 0.f};
    float acc1[4] = {0.f, 0.f, 0.f, 0.f};
    const float* xb0 = &xlds[(rg * 2 + 0) * 132];
    const float* xb1 = &xlds[(rg * 2 + 1) * 132];

    #pragma unroll 4
    for (int k = 0; k < IN_CH; ++k) {
        float4 b = *(const float4*)&wlds[k * HCDIM + cg * 4];
        float a0 = xb0[k];
        float a1 = xb1[k];
        acc0[0] = fmaf(a0, b.x, acc0[0]);
        acc0[1] = fmaf(a0, b.y, acc0[1]);
        acc0[2] = fmaf(a0, b.z, acc0[2]);
        acc0[3] = fmaf(a0, b.w, acc0[3]);
        acc1[0] = fmaf(a1, b.x, acc1[0]);
        acc1[1] = fmaf(a1, b.y, acc1[1]);
        acc1[2] = fmaf(a1, b.z, acc1[2]);
        acc1[3] = fmaf(a1, b.w, acc1[3]);
    }

    float sv[4], dv[4];
    #pragma unroll
    for (int j = 0; j < 4; ++j) { sv[j] = attS[cg * 4 + j]; dv[j] = attD[cg * 4 + j]; }

    #pragma unroll
    for (int i = 0; i < 2; ++i) {
        const float* accp = i ? acc1 : acc0;
        int row = rows0 + rg * 2 + i;
        bool ok = row < N;
        if (ok) {
            // pack 4 channels to bf16 (RN) and store 8B
            __hip_bfloat16 b0 = __float2bfloat16(accp[0]);
            __hip_bfloat16 b1 = __float2bfloat16(accp[1]);
            __hip_bfloat16 b2 = __float2bfloat16(accp[2]);
            __hip_bfloat16 b3 = __float2bfloat16(accp[3]);
            ushort4 pk;
            pk.x = *(unsigned short*)&b0; pk.y = *(unsigned short*)&b1;
            pk.z = *(unsigned short*)&b2; pk.w = *(unsigned short*)&b3;
            *(ushort4*)&xpb[(size_t)row * HCDIM + cg * 4] = pk;
        }
        float ps = accp[0]*sv[0] + accp[1]*sv[1] + accp[2]*sv[2] + accp[3]*sv[3];
        float pd = accp[0]*dv[0] + accp[1]*dv[1] + accp[2]*dv[2] + accp[3]*dv[3];
        ps += __shfl_xor(ps, 1); ps += __shfl_xor(ps, 2);
        pd += __shfl_xor(pd, 1); pd += __shfl_xor(pd, 2);
        if (ok && (cg & 3) == 0) {
            int h = cg >> 2;
            a_src[(size_t)row * NHEAD + h] = ps;
            a_dst[(size_t)row * NHEAD + h] = pd;
        }
    }
}

// ---------------------------------------------------------------------------
// CSR construction: 2-level exclusive scan -> packed scatter
// ---------------------------------------------------------------------------
__global__ __launch_bounds__(256) void scan_bsum(
    const int* __restrict__ counts, int N, int* __restrict__ bsums)
{
    __shared__ int sdata[256];
    const int b = blockIdx.x, t = threadIdx.x;
    int base = b * 2048 + t * 8;
    int s = 0;
    #pragma unroll
    for (int i = 0; i < 8; ++i) {
        int g = base + i;
        if (g < N) s += counts[g];
    }
    sdata[t] = s;
    __syncthreads();
    for (int off = 128; off > 0; off >>= 1) {
        if (t < off) sdata[t] += sdata[t + off];
        __syncthreads();
    }
    if (t == 0) bsums[b] = sdata[0];
}

__global__ void scan_offsets(const int* __restrict__ bsums, int nblk,
                             int* __restrict__ boffs, int* __restrict__ row_start,
                             int N, int E)
{
    const int lane = threadIdx.x & 63;
    if (nblk <= 64) {
        int v = (lane < nblk) ? bsums[lane] : 0;
        int s = v;
        #pragma unroll
        for (int off = 1; off < 64; off <<= 1) {
            int u = __shfl_up(s, off);
            if (lane >= off) s += u;
        }
        if (lane < nblk) boffs[lane] = s - v;
        if (lane == 0)   row_start[N] = E;
    } else if (lane == 0) {
        int run = 0;
        for (int b = 0; b < nblk; ++b) { boffs[b] = run; run += bsums[b]; }
        row_start[N] = E;
    }
}

__global__ __launch_bounds__(256) void scan_write(
    const int* __restrict__ counts, int N, const int* __restrict__ boffs,
    int* __restrict__ row_start, int* __restrict__ cursor)
{
    __shared__ int tsum[256];
    __shared__ int tex[256];
    const int b = blockIdx.x, t = threadIdx.x;
    int base = b * 2048 + t * 8;
    int v[8];
    int s = 0;
    #pragma unroll
    for (int i = 0; i < 8; ++i) {
        int g = base + i;
        v[i] = (g < N) ? counts[g] : 0;
        s += v[i];
    }
    tsum[t] = s;
    __syncthreads();
    if (t == 0) {
        int run = 0;
        for (int i = 0; i < 256; ++i) { tex[i] = run; run += tsum[i]; }
    }
    __syncthreads();
    int run = boffs[b] + tex[t];
    #pragma unroll
    for (int i = 0; i < 8; ++i) {
        int g = base + i;
        if (g < N) {
            row_start[g] = run;
            cursor[g]    = run;
            run += v[i];
        }
    }
}

__global__ void scatter_kernel(const int* __restrict__ srcv, const int* __restrict__ dstv,
                               int E, int* __restrict__ cursor, int2* __restrict__ plist)
{
    int i = blockIdx.x * blockDim.x + threadIdx.x;
    if (i < E) {
        int d = dstv[i];
        int pos = atomicAdd(&cursor[d], 1);
        plist[pos] = make_int2(srcv[i], i);   // one packed 8B scattered store
    }
}

// ---------------------------------------------------------------------------
// One wave per destination node.
// Fast path (deg <= 64, ~always): single pass — logits & exp stay in
// registers; a_src gathered ONCE. Generic chunked 3-phase path for deg > 64.
// ---------------------------------------------------------------------------
__global__ __launch_bounds__(256) void aggregate_kernel(
    const __hip_bfloat16* __restrict__ xp, const float* __restrict__ a_src,
    const float* __restrict__ a_dst, const float* __restrict__ bias,
    const int* __restrict__ row_start, const int2* __restrict__ plist,
    float* __restrict__ out, float* __restrict__ alpha_out, int N)
{
    __shared__ __align__(16) float al_f[4][256];  // per-wave: 64 edges x 4 heads
    __shared__ int sr[4][64];
    const int w    = threadIdx.x >> 6;
    const int lane = threadIdx.x & 63;
    const int n    = blockIdx.x * 4 + w;
    if (n >= N) return;

    const int beg = row_start[n];
    const int end = row_start[n + 1];
    const float bv = bias[lane];
    if (beg >= end) {                       // empty segment: out = bias
        out[(size_t)n * HCDIM + lane] = bv;
        return;
    }
    const int deg = end - beg;
    const float4 ad = *(const float4*)&a_dst[(size_t)n * NHEAD];
    const int h = lane >> 4;

    if (deg <= 64) {
        // ---------------- fast path: everything in registers ----------------
        float z0 = -INFINITY, z1 = -INFINITY, z2 = -INFINITY, z3 = -INFINITY;
        int s = 0, eid = 0;
        if (lane < deg) {
            int2 pe = plist[beg + lane];
            s = pe.x; eid = pe.y;
            float4 as = *(const float4*)&a_src[(size_t)s * NHEAD];
            z0 = as.x + ad.x; z0 = z0 > 0.f ? z0 : NEG_SLOPE * z0;
            z1 = as.y + ad.y; z1 = z1 > 0.f ? z1 : NEG_SLOPE * z1;
            z2 = as.z + ad.z; z2 = z2 > 0.f ? z2 : NEG_SLOPE * z2;
            z3 = as.w + ad.w; z3 = z3 > 0.f ? z3 : NEG_SLOPE * z3;
        }
        float m0 = z0, m1 = z1, m2 = z2, m3 = z3;
        #pragma unroll
        for (int off = 1; off < 64; off <<= 1) {
            m0 = fmaxf(m0, __shfl_xor(m0, off));
            m1 = fmaxf(m1, __shfl_xor(m1, off));
            m2 = fmaxf(m2, __shfl_xor(m2, off));
            m3 = fmaxf(m3, __shfl_xor(m3, off));
        }
        float e0 = 0.f, e1 = 0.f, e2 = 0.f, e3 = 0.f;
        if (lane < deg) {
            e0 = __expf(z0 - m0); e1 = __expf(z1 - m1);
            e2 = __expf(z2 - m2); e3 = __expf(z3 - m3);
        }
        float t0 = e0, t1 = e1, t2 = e2, t3 = e3;
        #pragma unroll
        for (int off = 1; off < 64; off <<= 1) {
            t0 += __shfl_xor(t0, off);
            t1 += __shfl_xor(t1, off);
            t2 += __shfl_xor(t2, off);
            t3 += __shfl_xor(t3, off);
        }
        if (lane < deg) {
            e0 *= 1.f / (t0 + 1e-16f);
            e1 *= 1.f / (t1 + 1e-16f);
            e2 *= 1.f / (t2 + 1e-16f);
            e3 *= 1.f / (t3 + 1e-16f);
            *(float4*)&alpha_out[(size_t)eid * NHEAD] = make_float4(e0, e1, e2, e3);
            *(float4*)&al_f[w][lane * 4] = make_float4(e0, e1, e2, e3);
            sr[w][lane] = s;
        }
        // same-wave LDS produce->consume: lockstep, compiler inserts lgkmcnt
        float acc = 0.f;
        int j = 0;
        for (; j + 4 <= deg; j += 4) {
            float a0 = al_f[w][(j+0) * 4 + h]; int s0 = sr[w][j+0];
            float a1 = al_f[w][(j+1) * 4 + h]; int s1 = sr[w][j+1];
            float a2 = al_f[w][(j+2) * 4 + h]; int s2 = sr[w][j+2];
            float a3 = al_f[w][(j+3) * 4 + h]; int s3 = sr[w][j+3];
            float x0 = bf2f(xp[(size_t)s0 * HCDIM + lane]);
            float x1 = bf2f(xp[(size_t)s1 * HCDIM + lane]);
            float x2 = bf2f(xp[(size_t)s2 * HCDIM + lane]);
            float x3 = bf2f(xp[(size_t)s3 * HCDIM + lane]);
            acc = fmaf(a0, x0, acc); acc = fmaf(a1, x1, acc);
            acc = fmaf(a2, x2, acc); acc = fmaf(a3, x3, acc);
        }
        for (; j < deg; ++j) {
            float a  = al_f[w][j * 4 + h];
            int   sj = sr[w][j];
            acc = fmaf(a, bf2f(xp[(size_t)sj * HCDIM + lane]), acc);
        }
        out[(size_t)n * HCDIM + lane] = acc + bv;
        return;
    }

    // ---------------- generic chunked path (deg > 64, rare) ----------------
    float m0 = -INFINITY, m1 = -INFINITY, m2 = -INFINITY, m3 = -INFINITY;
    for (int cb = beg; cb < end; cb += 64) {
        int idx = cb + lane;
        if (idx < end) {
            int2 pe = plist[idx];
            float4 as = *(const float4*)&a_src[(size_t)pe.x * NHEAD];
            float z0 = as.x + ad.x; z0 = z0 > 0.f ? z0 : NEG_SLOPE * z0;
            float z1 = as.y + ad.y; z1 = z1 > 0.f ? z1 : NEG_SLOPE * z1;
            float z2 = as.z + ad.z; z2 = z2 > 0.f ? z2 : NEG_SLOPE * z2;
            float z3 = as.w + ad.w; z3 = z3 > 0.f ? z3 : NEG_SLOPE * z3;
            m0 = fmaxf(m0, z0); m1 = fmaxf(m1, z1);
            m2 = fmaxf(m2, z2); m3 = fmaxf(m3, z3);
        }
    }
    #pragma unroll
    for (int off = 1; off < 64; off <<= 1) {
        m0 = fmaxf(m0, __shfl_xor(m0, off));
        m1 = fmaxf(m1, __shfl_xor(m1, off));
        m2 = fmaxf(m2, __shfl_xor(m2, off));
        m3 = fmaxf(m3, __shfl_xor(m3, off));
    }
    float t0 = 0.f, t1 = 0.f, t2 = 0.f, t3 = 0.f;
    for (int cb = beg; cb < end; cb += 64) {
        int idx = cb + lane;
        if (idx < end) {
            int2 pe = plist[idx];
            float4 as = *(const float4*)&a_src[(size_t)pe.x * NHEAD];
            float z0 = as.x + ad.x; z0 = z0 > 0.f ? z0 : NEG_SLOPE * z0;
            float z1 = as.y + ad.y; z1 = z1 > 0.f ? z1 : NEG_SLOPE * z1;
            float z2 = as.z + ad.z; z2 = z2 > 0.f ? z2 : NEG_SLOPE * z2;
            float z3 = as.w + ad.w; z3 = z3 > 0.f ? z3 : NEG_SLOPE * z3;
            t0 += __expf(z0 - m0); t1 += __expf(z1 - m1);
            t2 += __expf(z2 - m2); t3 += __expf(z3 - m3);
        }
    }
    #pragma unroll
    for (int off = 1; off < 64; off <<= 1) {
        t0 += __shfl_xor(t0, off);
        t1 += __shfl_xor(t1, off);
        t2 += __shfl_xor(t2, off);
        t3 += __shfl_xor(t3, off);
    }
    const float r0 = 1.f / (t0 + 1e-16f);
    const float r1 = 1.f / (t1 + 1e-16f);
    const float r2 = 1.f / (t2 + 1e-16f);
    const float r3 = 1.f / (t3 + 1e-16f);

    float acc = 0.f;
    for (int cb = beg; cb < end; cb += 64) {
        int idx = cb + lane;
        int nE = min(64, end - cb);
        if (idx < end) {
            int2 pe = plist[idx];
            float4 as = *(const float4*)&a_src[(size_t)pe.x * NHEAD];
            float z0 = as.x + ad.x; z0 = z0 > 0.f ? z0 : NEG_SLOPE * z0;
            float z1 = as.y + ad.y; z1 = z1 > 0.f ? z1 : NEG_SLOPE * z1;
            float z2 = as.z + ad.z; z2 = z2 > 0.f ? z2 : NEG_SLOPE * z2;
            float z3 = as.w + ad.w; z3 = z3 > 0.f ? z3 : NEG_SLOPE * z3;
            float e0 = __expf(z0 - m0) * r0;
            float e1 = __expf(z1 - m1) * r1;
            float e2 = __expf(z2 - m2) * r2;
            float e3 = __expf(z3 - m3) * r3;
            *(float4*)&alpha_out[(size_t)pe.y * NHEAD] = make_float4(e0, e1, e2, e3);
            *(float4*)&al_f[w][lane * 4] = make_float4(e0, e1, e2, e3);
            sr[w][lane] = pe.x;
        }
        for (int j = 0; j < nE; ++j) {
            float a  = al_f[w][j * 4 + h];
            int   sj = sr[w][j];
            acc = fmaf(a, bf2f(xp[(size_t)sj * HCDIM + lane]), acc);
        }
    }
    out[(size_t)n * HCDIM + lane] = acc + bv;
}

// ---------------------------------------------------------------------------
extern "C" void kernel_launch(void* const* d_in, const int* in_sizes, int n_in,
                              void* d_out, int out_size, void* d_ws, size_t ws_size,
                              hipStream_t stream)
{
    const float* x    = (const float*)d_in[0];
    const float* W    = (const float*)d_in[1];
    const float* attS = (const float*)d_in[2];
    const float* attD = (const float*)d_in[3];
    const float* bias = (const float*)d_in[4];
    const int*   ei   = (const int*)d_in[5];

    const int N = in_sizes[0] / IN_CH;
    const int E = in_sizes[5] / 2;
    const int* srcv = ei;
    const int* dstv = ei + E;

    // workspace carve-up (all 256B aligned)
    char* p = (char*)d_ws;
    __hip_bfloat16* xpb = (__hip_bfloat16*)p; p += align256((size_t)N * HCDIM * 2);
    float* a_src     = (float*)p; p += align256((size_t)N * NHEAD * 4);
    float* a_dst     = (float*)p; p += align256((size_t)N * NHEAD * 4);
    int*   counts    = (int*)p;   p += align256((size_t)N * 4);
    int*   cursor    = (int*)p;   p += align256((size_t)N * 4);
    int*   row_start = (int*)p;   p += align256(((size_t)N + 1) * 4);
    int*   bsums     = (int*)p;   p += align256(1024 * 4);
    int*   boffs     = (int*)p;   p += align256(1024 * 4);
    int2*  plist     = (int2*)p;  p += align256((size_t)E * 8);

    float* out       = (float*)d_out;
    float* out_ei    = out + (size_t)N * HCDIM;
    float* alpha_out = out_ei + 2 * (size_t)E;

    hipMemsetAsync(counts, 0, (size_t)N * 4, stream);

    const int GB = (N + 31) / 32;
    const int CB = (2 * E + 255) / 256;
    front_kernel<<<GB + CB, 256, 0, stream>>>(
        x, W, attS, attD, xpb, a_src, a_dst, N, GB, ei, E, out_ei, counts);

    const int nblk = (N + 2047) / 2048;
    scan_bsum<<<nblk, 256, 0, stream>>>(counts, N, bsums);
    scan_offsets<<<1, 64, 0, stream>>>(bsums, nblk, boffs, row_start, N, E);
    scan_write<<<nblk, 256, 0, stream>>>(counts, N, boffs, row_start, cursor);

    scatter_kernel<<<(E + 255) / 256, 256, 0, stream>>>(
        srcv, dstv, E, cursor, plist);

    aggregate_kernel<<<(N + 3) / 4, 256, 0, stream>>>(
        xpb, a_src, a_dst, bias, row_start, plist, out, alpha_out, N);
}